// Round 1
// baseline (254.282 us; speedup 1.0000x reference)
//
#include <hip/hip_runtime.h>
#include <stdint.h>

#define GLOBAL_AS __attribute__((address_space(1)))
#define LDS_AS    __attribute__((address_space(3)))

typedef int v4i  __attribute__((ext_vector_type(4)));
typedef int v16i __attribute__((ext_vector_type(16)));

__device__ __forceinline__ void gload_lds16(const void* g, void* l) {
    __builtin_amdgcn_global_load_lds((GLOBAL_AS uint32_t*)g, (LDS_AS uint32_t*)l, 16, 0, 0);
}

// ---------------- kernel 1 (fused): weight-max (blocks 0..47) + act quantize (blocks 48+) ----
// wmax part: max |tanh(w)| over 3*3*256*256 weights -> atomicMax on float bits (all >= 0).
// xq part:   quantize acts -> int8 {0..3} into zero-padded [32][58][58][256].
__global__ void k_xq_wmax(const float* __restrict__ x, const float* __restrict__ w,
                          int8_t* __restrict__ xqp, unsigned* __restrict__ maxbits) {
    const int bid = blockIdx.x;
    if (bid < 48) {
        // 48 blocks * 256 thr = 12288 threads, 147456 float4s, 12 each
        int t = bid * 256 + threadIdx.x;
        const float4* w4 = (const float4*)w;
        float m = 0.f;
        for (int i = t; i < 147456; i += 12288) {
            float4 v = w4[i];
            m = fmaxf(m, fmaxf(fmaxf(fabsf(tanhf(v.x)), fabsf(tanhf(v.y))),
                               fmaxf(fabsf(tanhf(v.z)), fabsf(tanhf(v.w)))));
        }
#pragma unroll
        for (int off = 32; off > 0; off >>= 1)
            m = fmaxf(m, __shfl_xor(m, off, 64));
        if ((threadIdx.x & 63) == 0) atomicMax(maxbits, __float_as_uint(m));
        return;
    }
    int t = (bid - 48) * 256 + threadIdx.x;   // 32*58*58*16 threads, 16 bytes each
    int g  = t & 15;
    int p  = t >> 4;
    int xp = p % 58;
    int q  = p / 58;
    int yp = q % 58;
    int n  = q / 58;
    int4 r;
    if (yp == 0 || yp == 57 || xp == 0 || xp == 57) {
        r = make_int4(0, 0, 0, 0);
    } else {
        const float4* px = (const float4*)(x + (((long)((n * 56 + (yp - 1)) * 56 + (xp - 1))) << 8) + g * 16);
        int wds[4];
#pragma unroll
        for (int jj = 0; jj < 4; ++jj) {
            float4 v = px[jj];
            int b0 = (int)rintf(fminf(fmaxf(v.x, 0.f), 1.f) * 3.f);
            int b1 = (int)rintf(fminf(fmaxf(v.y, 0.f), 1.f) * 3.f);
            int b2 = (int)rintf(fminf(fmaxf(v.z, 0.f), 1.f) * 3.f);
            int b3 = (int)rintf(fminf(fmaxf(v.w, 0.f), 1.f) * 3.f);
            wds[jj] = b0 | (b1 << 8) | (b2 << 16) | (b3 << 24);
        }
        r = make_int4(wds[0], wds[1], wds[2], wds[3]);
    }
    *(int4*)(xqp + ((long)t << 4)) = r;
}

// ---------------- kernel 2: quantize weights -> int8 {-3,-1,1,3}, layout [co][tap*256+ci] ----
__global__ void k_wq(const float* __restrict__ w, const unsigned* __restrict__ maxbits,
                     int8_t* __restrict__ wqt) {
    int t = blockIdx.x * 256 + threadIdx.x;   // 36864 threads
    int co = t & 255;
    int kblk = t >> 8;                        // 0..143, 16 k-values each
    float inv = 0.5f / __uint_as_float(*maxbits);
    int8_t b[16];
#pragma unroll
    for (int i = 0; i < 16; ++i) {
        float tv = tanhf(w[(long)(kblk * 16 + i) * 256 + co]);   // HWIO [k][co]
        int qi = (int)rintf((tv * inv + 0.5f) * 3.0f);           // 0..3, half-even = jnp.round
        b[i] = (int8_t)(2 * qi - 3);                             // {-3,-1,1,3}
    }
    *(int4*)(wqt + (long)co * 2304 + kblk * 16) = *(int4*)b;
}

// ---------------- kernel 3: pipelined implicit-GEMM conv, i8 MFMA 32x32x32 ------------------
// C[100352][256] = A[M][2304] * B[2304][256]; BM=BN=128, BK=128B, 18 K-iters.
// Double-buffered LDS + raw s_barrier + s_waitcnt vmcnt(8): the 8 prefetch loads for iter
// i+1 stay IN FLIGHT across the barrier (AITER-style), so global latency overlaps compute.
// XCD swizzle: 1D grid 1568; work=(bid&7)*196+(bid>>3); co=work&1, mtile=work>>1.
//   -> each XCD runs 32 consecutive m-tiles x both co halves: A-halo+B working set ~3.7MB
//      fits the 4MB per-XCD L2 (A tap-halo and co-pair reuse become L2 hits, not LLC).
#define BM 128
#define BN 128

__global__ __launch_bounds__(256) void k_conv(const int8_t* __restrict__ xqp,
                                              const int8_t* __restrict__ wqt,
                                              float* __restrict__ out) {
    __shared__ int8_t sA[2][BM * 128];   // 2 x 16 KB
    __shared__ int8_t sB[2][BN * 128];   // 2 x 16 KB

    const int tid    = threadIdx.x;
    const int wv     = tid >> 6;
    const int lane   = tid & 63;
    const int orig   = blockIdx.x;                  // 1568 blocks, 1568 % 8 == 0 -> bijective
    const int work   = (orig & 7) * 196 + (orig >> 3);
    const int coBase = (work & 1) * BN;
    const int mBase  = (work >> 1) * BM;

    // staging: instruction (wv, j) covers tile rows rbase..rbase+7, rbase = wv*8 + j*32
    // lane -> row = rbase + (lane>>3), phys chunk p = lane&7, global chunk g = p ^ (row&7)
    const int lr = lane >> 3;
    const int lp = lane & 7;
    const int8_t* aB[4];
    const int8_t* bB[4];
#pragma unroll
    for (int j = 0; j < 4; ++j) {
        int r = wv * 8 + j * 32 + lr;
        int g = lp ^ (r & 7);
        int m = mBase + r;
        int n = m / 3136;
        int rem = m - n * 3136;
        int y = rem / 56;
        int x = rem - y * 56;
        aB[j] = xqp + (((long)((n * 58 + y) * 58 + x)) << 8) + g * 16;
        bB[j] = wqt + (long)(coBase + r) * 2304 + g * 16;
    }

    v16i acc[2][2];
#pragma unroll
    for (int a = 0; a < 2; ++a)
#pragma unroll
        for (int b = 0; b < 2; ++b)
#pragma unroll
            for (int r = 0; r < 16; ++r) acc[a][b][r] = 0;

    const int wm  = (wv & 1) * 64;
    const int wn  = (wv >> 1) * 64;
    const int l31 = lane & 31;
    const int hi  = lane >> 5;

    // fragment row offsets + per-row XOR terms
    const int rA0 = (wm + l31) * 128;       const int axr0 = ((wm + l31) & 7) << 4;
    const int rA1 = (wm + 32 + l31) * 128;  const int axr1 = ((wm + 32 + l31) & 7) << 4;
    const int rB0 = (wn + l31) * 128;       const int bxr0 = ((wn + l31) & 7) << 4;
    const int rB1 = (wn + 32 + l31) * 128;  const int bxr1 = ((wn + 32 + l31) & 7) << 4;

    auto issue = [&](int it, int b) {
        int tap = it >> 1;
        int ky  = tap / 3;
        int kx  = tap - ky * 3;
        int aOff = ((ky * 58 + kx) << 8) + (it & 1) * 128;
        int bOff = tap * 256 + (it & 1) * 128;
#pragma unroll
        for (int j = 0; j < 4; ++j) {
            gload_lds16(aB[j] + aOff, &sA[b][(wv * 8 + j * 32) * 128]);
            gload_lds16(bB[j] + bOff, &sB[b][(wv * 8 + j * 32) * 128]);
        }
    };

    auto compute = [&](int b) {
        const int8_t* pA = sA[b];
        const int8_t* pB = sB[b];
        __builtin_amdgcn_s_setprio(1);       // T5: favor the MFMA-entering wave; the co-resident
#pragma unroll                               // block on this CU is in its staging phase
        for (int kk = 0; kk < 4; ++kk) {
            const int kc = (kk * 2 + hi) << 4;   // K-chunk byte offset
            v4i a0 = *(const v4i*)(pA + rA0 + (kc ^ axr0));
            v4i a1 = *(const v4i*)(pA + rA1 + (kc ^ axr1));
            v4i b0 = *(const v4i*)(pB + rB0 + (kc ^ bxr0));
            v4i b1 = *(const v4i*)(pB + rB1 + (kc ^ bxr1));
            acc[0][0] = __builtin_amdgcn_mfma_i32_32x32x32_i8(a0, b0, acc[0][0], 0, 0, 0);
            acc[0][1] = __builtin_amdgcn_mfma_i32_32x32x32_i8(a0, b1, acc[0][1], 0, 0, 0);
            acc[1][0] = __builtin_amdgcn_mfma_i32_32x32x32_i8(a1, b0, acc[1][0], 0, 0, 0);
            acc[1][1] = __builtin_amdgcn_mfma_i32_32x32x32_i8(a1, b1, acc[1][1], 0, 0, 0);
        }
        __builtin_amdgcn_s_setprio(0);
    };

    // -------- pipelined K-loop --------
    issue(0, 0);
#pragma unroll 2
    for (int it = 0; it < 17; ++it) {
        issue(it + 1, (it + 1) & 1);                    // prefetch next buffer (8 loads in flight)
        asm volatile("s_waitcnt vmcnt(8)" ::: "memory"); // wait ONLY for current buffer's 8 loads
        __builtin_amdgcn_s_barrier();
        asm volatile("" ::: "memory");
        compute(it & 1);
        asm volatile("" ::: "memory");                   // all waves done reading buf before overwrite
        __builtin_amdgcn_s_barrier();
        asm volatile("" ::: "memory");
    }
    asm volatile("s_waitcnt vmcnt(0)" ::: "memory");     // last iter: drain remaining 8
    __builtin_amdgcn_s_barrier();
    asm volatile("" ::: "memory");
    compute(1);                                          // it=17 -> buf 1

    // epilogue: 32x32 C/D layout col=lane&31, row=(reg&3)+8*(reg>>2)+4*(lane>>5); out = acc/9
    const float s = 1.0f / 9.0f;
#pragma unroll
    for (int mt = 0; mt < 2; ++mt) {
#pragma unroll
        for (int nt = 0; nt < 2; ++nt) {
            const int ocol = coBase + wn + nt * 32 + l31;
#pragma unroll
            for (int reg = 0; reg < 16; ++reg) {
                const int row = (reg & 3) + 8 * (reg >> 2) + 4 * hi;
                const long orow = mBase + wm + mt * 32 + row;
                out[orow * 256 + ocol] = (float)acc[mt][nt][reg] * s;
            }
        }
    }
}

extern "C" void kernel_launch(void* const* d_in, const int* in_sizes, int n_in,
                              void* d_out, int out_size, void* d_ws, size_t ws_size,
                              hipStream_t stream) {
    const float* x = (const float*)d_in[0];   // (32,56,56,256) NHWC fp32
    const float* w = (const float*)d_in[1];   // (3,3,256,256) HWIO fp32
    float* out = (float*)d_out;               // (32,56,56,256) fp32

    unsigned* maxbits = (unsigned*)d_ws;
    int8_t* wqt = (int8_t*)d_ws + 4096;              // 2304*256 = 589824 B, [co][k]
    int8_t* xqp = (int8_t*)d_ws + 4096 + 589824;     // 32*58*58*256 = 27,557,888 B

    hipMemsetAsync(maxbits, 0, 4, stream);           // ws poisoned 0xAA -> zero for atomicMax
    k_xq_wmax<<<48 + 6728, 256, 0, stream>>>(x, w, xqp, maxbits);  // wmax hides under xq
    k_wq<<<144, 256, 0, stream>>>(w, maxbits, wqt);
    k_conv<<<1568, 256, 0, stream>>>(xqp, wqt, out);
}

// Round 3
// 229.660 us; speedup vs baseline: 1.1072x; 1.1072x over previous
//
#include <hip/hip_runtime.h>
#include <stdint.h>

#define GLOBAL_AS __attribute__((address_space(1)))
#define LDS_AS    __attribute__((address_space(3)))

typedef int   v4i  __attribute__((ext_vector_type(4)));
typedef int   v8i  __attribute__((ext_vector_type(8)));
typedef float v16f __attribute__((ext_vector_type(16)));

__device__ __forceinline__ void gload_lds16(const void* g, void* l) {
    __builtin_amdgcn_global_load_lds((GLOBAL_AS uint32_t*)g, (LDS_AS uint32_t*)l, 16, 0, 0);
}

// fp4 e2m1 encodings: {0,1,2,3} -> {0x0,0x2,0x4,0x5}; {-3,-1,1,3} -> {0xD,0xA,0x2,0x5}
// shift-LUTs (stay in registers, no scratch):
//   act   nibble = (0x5420 >> (q*4)) & 0xF
//   wght  nibble = (0x52AD >> (q*4)) & 0xF   (q = 0..3 maps to -3,-1,1,3)

// ---------------- kernel 1 (fused): weight-max (blocks 0..47) + act quantize -> fp4 ----------
// xq part: quantize acts -> fp4 {0..3} packed 2/byte into zero-padded [32][58][58][128B].
__global__ void k_xq_wmax(const float* __restrict__ x, const float* __restrict__ w,
                          int8_t* __restrict__ xqp, unsigned* __restrict__ maxbits) {
    const int bid = blockIdx.x;
    if (bid < 48) {
        int t = bid * 256 + threadIdx.x;
        const float4* w4 = (const float4*)w;
        float m = 0.f;
        for (int i = t; i < 147456; i += 12288) {
            float4 v = w4[i];
            m = fmaxf(m, fmaxf(fmaxf(fabsf(tanhf(v.x)), fabsf(tanhf(v.y))),
                               fmaxf(fabsf(tanhf(v.z)), fabsf(tanhf(v.w)))));
        }
#pragma unroll
        for (int off = 32; off > 0; off >>= 1)
            m = fmaxf(m, __shfl_xor(m, off, 64));
        if ((threadIdx.x & 63) == 0) atomicMax(maxbits, __float_as_uint(m));
        return;
    }
    int t = (bid - 48) * 256 + threadIdx.x;   // 32*58*58*8 threads, 16 bytes (32 ch) each
    int g  = t & 7;
    int p  = t >> 3;
    int xp = p % 58;
    int q  = p / 58;
    int yp = q % 58;
    int n  = q / 58;
    int4 r;
    if (yp == 0 || yp == 57 || xp == 0 || xp == 57) {
        r = make_int4(0, 0, 0, 0);
    } else {
        const float4* px = (const float4*)(x + (((long)((n * 56 + (yp - 1)) * 56 + (xp - 1))) << 8) + g * 32);
        int wds[4];
#pragma unroll
        for (int jj = 0; jj < 4; ++jj) {
            float4 v0 = px[jj * 2];
            float4 v1 = px[jj * 2 + 1];
            int q0 = (int)rintf(fminf(fmaxf(v0.x, 0.f), 1.f) * 3.f);
            int q1 = (int)rintf(fminf(fmaxf(v0.y, 0.f), 1.f) * 3.f);
            int q2 = (int)rintf(fminf(fmaxf(v0.z, 0.f), 1.f) * 3.f);
            int q3 = (int)rintf(fminf(fmaxf(v0.w, 0.f), 1.f) * 3.f);
            int q4 = (int)rintf(fminf(fmaxf(v1.x, 0.f), 1.f) * 3.f);
            int q5 = (int)rintf(fminf(fmaxf(v1.y, 0.f), 1.f) * 3.f);
            int q6 = (int)rintf(fminf(fmaxf(v1.z, 0.f), 1.f) * 3.f);
            int q7 = (int)rintf(fminf(fmaxf(v1.w, 0.f), 1.f) * 3.f);
            wds[jj] = ((0x5420 >> (q0 << 2)) & 0xF)        | (((0x5420 >> (q1 << 2)) & 0xF) << 4)
                    | (((0x5420 >> (q2 << 2)) & 0xF) << 8) | (((0x5420 >> (q3 << 2)) & 0xF) << 12)
                    | (((0x5420 >> (q4 << 2)) & 0xF) << 16)| (((0x5420 >> (q5 << 2)) & 0xF) << 20)
                    | (((0x5420 >> (q6 << 2)) & 0xF) << 24)| (((0x5420 >> (q7 << 2)) & 0xF) << 28);
        }
        r = make_int4(wds[0], wds[1], wds[2], wds[3]);
    }
    *(int4*)(xqp + ((long)t << 4)) = r;
}

// ---------------- kernel 2: quantize weights -> fp4 {-3,-1,1,3}, layout [co][tap*128+ci/2] ---
__global__ void k_wq(const float* __restrict__ w, const unsigned* __restrict__ maxbits,
                     int8_t* __restrict__ wqt) {
    int t = blockIdx.x * 256 + threadIdx.x;   // 18432 threads
    int co = t & 255;
    int kblk = t >> 8;                        // 0..71, 32 k-values each
    float inv = 0.5f / __uint_as_float(*maxbits);
    uint8_t b[16];
#pragma unroll
    for (int j = 0; j < 16; ++j) {
        float t0 = tanhf(w[(long)(kblk * 32 + 2 * j) * 256 + co]);     // HWIO [k][co]
        float t1 = tanhf(w[(long)(kblk * 32 + 2 * j + 1) * 256 + co]);
        int q0 = (int)rintf((t0 * inv + 0.5f) * 3.0f);                 // 0..3, half-even
        int q1 = (int)rintf((t1 * inv + 0.5f) * 3.0f);
        b[j] = (uint8_t)(((0x52AD >> (q0 << 2)) & 0xF) | (((0x52AD >> (q1 << 2)) & 0xF) << 4));
    }
    *(int4*)(wqt + (long)co * 1152 + kblk * 16) = *(int4*)b;
}

// ---------------- kernel 3: pipelined implicit-GEMM conv, MX-fp4 MFMA 32x32x64 --------------
// C[100352][256] = A[M][2304] * B[2304][256] in fp4 (1152 B/row); BM=BN=128, 128B/row/iter,
// 9 K-iters (one conv tap each). Scale = e8m0(127) = 1.0 -> exact integer math in f32 acc.
// Double-buffered LDS + raw s_barrier + s_waitcnt vmcnt(8) (prefetch stays in flight).
// XCD swizzle: work=(bid&7)*196+(bid>>3); co=work&1, mtile=work>>1 (per-XCD L2 locality).
#define BM 128
#define BN 128

__global__ __launch_bounds__(256) void k_conv(const int8_t* __restrict__ xqp,
                                              const int8_t* __restrict__ wqt,
                                              float* __restrict__ out) {
    __shared__ int8_t sA[2][BM * 128];   // 2 x 16 KB (128B = 256 fp4 K-elems per row)
    __shared__ int8_t sB[2][BN * 128];   // 2 x 16 KB

    const int tid    = threadIdx.x;
    const int wv     = tid >> 6;
    const int lane   = tid & 63;
    const int orig   = blockIdx.x;                  // 1568 blocks, 1568 % 8 == 0 -> bijective
    const int work   = (orig & 7) * 196 + (orig >> 3);
    const int coBase = (work & 1) * BN;
    const int mBase  = (work >> 1) * BM;

    // staging: instruction (wv, j) covers tile rows rbase..rbase+7, rbase = wv*8 + j*32
    // lane -> row = rbase + (lane>>3), phys chunk p = lane&7, global chunk g = p ^ (row&7)
    const int lr = lane >> 3;
    const int lp = lane & 7;
    const int8_t* aB[4];
    const int8_t* bB[4];
#pragma unroll
    for (int j = 0; j < 4; ++j) {
        int r = wv * 8 + j * 32 + lr;
        int g = lp ^ (r & 7);
        int m = mBase + r;
        int n = m / 3136;
        int rem = m - n * 3136;
        int y = rem / 56;
        int x = rem - y * 56;
        aB[j] = xqp + (((long)((n * 58 + y) * 58 + x)) << 7) + g * 16;   // 128 B per pixel
        bB[j] = wqt + (long)(coBase + r) * 1152 + g * 16;
    }

    v16f acc[2][2];
#pragma unroll
    for (int a = 0; a < 2; ++a)
#pragma unroll
        for (int b = 0; b < 2; ++b)
#pragma unroll
            for (int r = 0; r < 16; ++r) acc[a][b][r] = 0.f;

    const int wm  = (wv & 1) * 64;
    const int wn  = (wv >> 1) * 64;
    const int l31 = lane & 31;
    const int hi  = lane >> 5;

    // fragment row offsets + per-row XOR terms (byte geometry identical to i8 version)
    const int rA0 = (wm + l31) * 128;       const int axr0 = ((wm + l31) & 7) << 4;
    const int rA1 = (wm + 32 + l31) * 128;  const int axr1 = ((wm + 32 + l31) & 7) << 4;
    const int rB0 = (wn + l31) * 128;       const int bxr0 = ((wn + l31) & 7) << 4;
    const int rB1 = (wn + 32 + l31) * 128;  const int bxr1 = ((wn + 32 + l31) & 7) << 4;

    auto issue = [&](int it, int b) {
        int ky  = it / 3;                    // iter == conv tap now
        int kx  = it - ky * 3;
        int aOff = (ky * 58 + kx) << 7;      // tap offset in padded fp4 image
        int bOff = it << 7;                  // tap*128 B in weight row
#pragma unroll
        for (int j = 0; j < 4; ++j) {
            gload_lds16(aB[j] + aOff, &sA[b][(wv * 8 + j * 32) * 128]);
            gload_lds16(bB[j] + bOff, &sB[b][(wv * 8 + j * 32) * 128]);
        }
    };

    const int SC = 0x7F7F7F7F;               // e8m0 127 -> scale 1.0 for every block

    auto compute = [&](int b) {
        const int8_t* pA = sA[b];
        const int8_t* pB = sB[b];
        __builtin_amdgcn_s_setprio(1);
#pragma unroll
        for (int kk = 0; kk < 4; ++kk) {
            const int kc = (kk * 2 + hi) << 4;   // 16B = 32 fp4 K-elems (this lane's K-half)
            v4i a0 = *(const v4i*)(pA + rA0 + (kc ^ axr0));
            v4i a1 = *(const v4i*)(pA + rA1 + (kc ^ axr1));
            v4i b0 = *(const v4i*)(pB + rB0 + (kc ^ bxr0));
            v4i b1 = *(const v4i*)(pB + rB1 + (kc ^ bxr1));
            v8i A0 = {a0[0], a0[1], a0[2], a0[3], 0, 0, 0, 0};   // fp4: data in v[0:3]
            v8i A1 = {a1[0], a1[1], a1[2], a1[3], 0, 0, 0, 0};
            v8i B0 = {b0[0], b0[1], b0[2], b0[3], 0, 0, 0, 0};
            v8i B1 = {b1[0], b1[1], b1[2], b1[3], 0, 0, 0, 0};
            acc[0][0] = __builtin_amdgcn_mfma_scale_f32_32x32x64_f8f6f4(A0, B0, acc[0][0], 4, 4, 0, SC, 0, SC);
            acc[0][1] = __builtin_amdgcn_mfma_scale_f32_32x32x64_f8f6f4(A0, B1, acc[0][1], 4, 4, 0, SC, 0, SC);
            acc[1][0] = __builtin_amdgcn_mfma_scale_f32_32x32x64_f8f6f4(A1, B0, acc[1][0], 4, 4, 0, SC, 0, SC);
            acc[1][1] = __builtin_amdgcn_mfma_scale_f32_32x32x64_f8f6f4(A1, B1, acc[1][1], 4, 4, 0, SC, 0, SC);
        }
        __builtin_amdgcn_s_setprio(0);
    };

    // -------- pipelined K-loop: 9 iters (one tap each) --------
    issue(0, 0);
#pragma unroll 2
    for (int it = 0; it < 8; ++it) {
        issue(it + 1, (it + 1) & 1);                    // prefetch next buffer (8 loads in flight)
        asm volatile("s_waitcnt vmcnt(8)" ::: "memory"); // wait ONLY for current buffer's 8 loads
        __builtin_amdgcn_s_barrier();
        asm volatile("" ::: "memory");
        compute(it & 1);
        asm volatile("" ::: "memory");                   // all waves done reading buf before overwrite
        __builtin_amdgcn_s_barrier();
        asm volatile("" ::: "memory");
    }
    asm volatile("s_waitcnt vmcnt(0)" ::: "memory");     // last iter: drain remaining 8
    __builtin_amdgcn_s_barrier();
    asm volatile("" ::: "memory");
    compute(0);                                          // it=8 -> buf 0

    // epilogue: 32x32 C/D layout col=lane&31, row=(reg&3)+8*(reg>>2)+4*(lane>>5); out = acc/9
    const float s = 1.0f / 9.0f;
#pragma unroll
    for (int mt = 0; mt < 2; ++mt) {
#pragma unroll
        for (int nt = 0; nt < 2; ++nt) {
            const int ocol = coBase + wn + nt * 32 + l31;
#pragma unroll
            for (int reg = 0; reg < 16; ++reg) {
                const int row = (reg & 3) + 8 * (reg >> 2) + 4 * hi;
                const long orow = mBase + wm + mt * 32 + row;
                out[orow * 256 + ocol] = acc[mt][nt][reg] * s;
            }
        }
    }
}

extern "C" void kernel_launch(void* const* d_in, const int* in_sizes, int n_in,
                              void* d_out, int out_size, void* d_ws, size_t ws_size,
                              hipStream_t stream) {
    const float* x = (const float*)d_in[0];   // (32,56,56,256) NHWC fp32
    const float* w = (const float*)d_in[1];   // (3,3,256,256) HWIO fp32
    float* out = (float*)d_out;               // (32,56,56,256) fp32

    unsigned* maxbits = (unsigned*)d_ws;
    int8_t* wqt = (int8_t*)d_ws + 4096;              // 256*1152 = 294912 B, [co][k/2]
    int8_t* xqp = (int8_t*)d_ws + 4096 + 294912;     // 32*58*58*128 = 13,778,944 B

    hipMemsetAsync(maxbits, 0, 4, stream);           // ws poisoned 0xAA -> zero for atomicMax
    k_xq_wmax<<<48 + 3364, 256, 0, stream>>>(x, w, xqp, maxbits);  // wmax hides under xq
    k_wq<<<72, 256, 0, stream>>>(w, maxbits, wqt);
    k_conv<<<1568, 256, 0, stream>>>(xqp, wqt, out);
}